// Round 4
// baseline (1382.594 us; speedup 1.0000x reference)
//
#include <hip/hip_runtime.h>
#include <hip/hip_bf16.h>
#include <math.h>

typedef __attribute__((ext_vector_type(8))) short short8;   // 8 bf16 = 16B
typedef __attribute__((ext_vector_type(4))) short bf4;      // 4 bf16 = 8B
typedef __attribute__((ext_vector_type(4))) float f32x4;

#define BN   8
#define TSQ  2048
#define HD   512
#define TDIM 256
#define SDIM 192
#define SCALE 0.04419417382415922f

// ws layout (bytes)
#define OFFB_G   0
#define OFFB_HB  2097152
#define OFFB_HT  4194304
#define OFFB_HS  20971520

static __device__ __forceinline__ short f2bf(float f) {
    __hip_bfloat16 h = __float2bfloat16(f);
    return *(short*)&h;
}

// ---------------- G precompute: G[k][ci][h] = sum_co conv_w[ci,co,k]*time_w[co,h]
__global__ void k_G(const float* __restrict__ conv_w, const float* __restrict__ time_w,
                    float* __restrict__ G) {
    const int ci = blockIdx.x & 255;
    const int kk = blockIdx.x >> 8;
    const int tid = threadIdx.x;
    __shared__ float cw[256];
    cw[tid] = conv_w[(ci * 256 + tid) * 4 + kk];
    __syncthreads();
    float a0 = 0.f, a1 = 0.f;
    for (int co = 0; co < 256; ++co) {
        float w = cw[co];
        a0 += w * time_w[co * HD + tid];
        a1 += w * time_w[co * HD + tid + 256];
    }
    G[((kk * 256) + ci) * HD + tid] = a0;
    G[((kk * 256) + ci) * HD + tid + 256] = a1;
}

__global__ void k_hbias(const float* __restrict__ conv_b, const float* __restrict__ time_w,
                        const float* __restrict__ time_b, float* __restrict__ hb) {
    const int h = blockIdx.x * 256 + threadIdx.x;
    float a = time_b[h];
    for (int co = 0; co < 256; ++co) a += conv_b[co] * time_w[co * HD + h];
    hb[h] = a;
}

// ---------------- H_time GEMM (fused convT + linear) -> bf16
__global__ void k_htime(const float* __restrict__ X, const float* __restrict__ G,
                        const float* __restrict__ hb, __hip_bfloat16* __restrict__ HT) {
    const int z  = blockIdx.z;
    const int tid = threadIdx.x;
    __shared__ float As[64][21];
    __shared__ float Bs[16][68];

    const int ridx0 = blockIdx.x * 64;
    const int b  = ridx0 >> 10;
    const int m0 = ridx0 & 1023;
    const int col0 = blockIdx.y * 64;
    const int ga = z ? 2 : 1;
    const int gb = z ? 0 : 3;
    const int dm = z ? 1 : -1;

    const int lr = tid >> 2;
    const int lc = (tid & 3) * 4;
    const int bkr = tid >> 4;
    const int bc  = (tid & 15) * 4;
    const int tr = tid >> 4, tc = tid & 15;
    const int r0 = tr * 4, c0 = tc * 4;

    float acc[4][4] = {};

    for (int kk = 0; kk < 512; kk += 16) {
        {
            int k = kk + lc;
            int m = m0 + lr;
            int mm = m, ko = k;
            bool valid = true;
            if (k >= 256) { mm = m + dm; ko = k - 256; valid = (mm >= 0) && (mm < 1024); }
            float4 v = make_float4(0.f, 0.f, 0.f, 0.f);
            if (valid) v = *(const float4*)(X + ((b << 10) + mm) * TDIM + ko);
            As[lr][lc] = v.x; As[lr][lc + 1] = v.y; As[lr][lc + 2] = v.z; As[lr][lc + 3] = v.w;
        }
        {
            int k = kk + bkr;
            const float* Bp = (k < 256) ? (G + (ga * 256 + k) * HD)
                                        : (G + (gb * 256 + (k - 256)) * HD);
            float4 v = *(const float4*)(Bp + col0 + bc);
            *(float4*)&Bs[bkr][bc] = v;
        }
        __syncthreads();
#pragma unroll
        for (int kc = 0; kc < 16; ++kc) {
            float a[4], bb[4];
#pragma unroll
            for (int i = 0; i < 4; ++i) a[i] = As[r0 + i][kc];
#pragma unroll
            for (int j = 0; j < 4; ++j) bb[j] = Bs[kc][c0 + j];
#pragma unroll
            for (int i = 0; i < 4; ++i)
#pragma unroll
                for (int j = 0; j < 4; ++j) acc[i][j] += a[i] * bb[j];
        }
        __syncthreads();
    }
#pragma unroll
    for (int i = 0; i < 4; ++i) {
        int m = m0 + r0 + i;
        int t = 2 * m + z;
        __hip_bfloat16* op = HT + ((size_t)(b * TSQ) + t) * HD + col0;
#pragma unroll
        for (int j = 0; j < 4; ++j) op[c0 + j] = __float2bfloat16(acc[i][j] + hb[col0 + c0 + j]);
    }
}

// ---------------- H_spec GEMM -> bf16
__global__ void k_hspec(const float* __restrict__ S, const float* __restrict__ spec_w,
                        const float* __restrict__ spec_b, __hip_bfloat16* __restrict__ HS) {
    const int tid = threadIdx.x;
    __shared__ float As[64][21];
    __shared__ float Bs[16][68];

    const int row0 = blockIdx.x * 64;
    const int b  = row0 >> 11;
    const int t0 = row0 & 2047;
    const int col0 = blockIdx.y * 64;

    const int jc   = tid >> 4;
    const int toff = (tid & 15) * 4;
    const int tr = tid >> 4, tc = tid & 15;
    const int r0 = tr * 4, c0 = tc * 4;

    float acc[4][4] = {};

    for (int kk = 0; kk < 192; kk += 16) {
        int j = kk + jc;
        float4 v = *(const float4*)(S + ((size_t)(b * SDIM + j)) * TSQ + t0 + toff);
        As[toff][jc] = v.x; As[toff + 1][jc] = v.y; As[toff + 2][jc] = v.z; As[toff + 3][jc] = v.w;
        float4 w = *(const float4*)(spec_w + j * HD + col0 + tc * 4);
        *(float4*)&Bs[jc][tc * 4] = w;
        __syncthreads();
#pragma unroll
        for (int kc = 0; kc < 16; ++kc) {
            float a[4], bb[4];
#pragma unroll
            for (int i = 0; i < 4; ++i) a[i] = As[r0 + i][kc];
#pragma unroll
            for (int j2 = 0; j2 < 4; ++j2) bb[j2] = Bs[kc][c0 + j2];
#pragma unroll
            for (int i = 0; i < 4; ++i)
#pragma unroll
                for (int j2 = 0; j2 < 4; ++j2) acc[i][j2] += a[i] * bb[j2];
        }
        __syncthreads();
    }
#pragma unroll
    for (int i = 0; i < 4; ++i) {
        __hip_bfloat16* op = HS + ((size_t)(b * TSQ) + t0 + r0 + i) * HD + col0;
#pragma unroll
        for (int j2 = 0; j2 < 4; ++j2) op[c0 + j2] = __float2bfloat16(acc[i][j2] + spec_b[col0 + c0 + j2]);
    }
}

// ---------------- MFMA flash attention, V == K, bf16 in, fp32 out
// Block: 512 thr (8 waves), q-tile 128 (16/wave), KVB=32, 1 block/CU.
// Pipeline: reg-staged next tile (T14), raw s_barrier (no vmcnt drain),
// defer-max softmax (THR=8), conflict-free staging layout.
#define SM_K  0
#define SM_VT 32768
#define SM_P  (32768 + 40960)
#define SMEM_FLASH (32768 + 40960 + 10240)

__global__ __launch_bounds__(512, 2)
void k_flash(const __hip_bfloat16* __restrict__ HTb, const __hip_bfloat16* __restrict__ HSb,
             float* __restrict__ out) {
    extern __shared__ char smem[];
    ushort* Kl = (ushort*)(smem + SM_K);    // [32][512]: elem at s*512 + (h ^ ((s&7)<<3))
    ushort* Vt = (ushort*)(smem + SM_VT);   // [512][40]: Vt[h*40+s] = K[s][h]
    ushort* Pl = (ushort*)(smem + SM_P);    // per wave [16][40]

    const int pass = blockIdx.y;
    const __hip_bfloat16* Qg = pass ? HSb : HTb;
    const __hip_bfloat16* Kg = pass ? HTb : HSb;
    const int b  = blockIdx.x & 7;          // batch -> XCD
    const int qt = blockIdx.x >> 3;         // 0..15
    const int tid = threadIdx.x;
    const int w = tid >> 6;
    const int l = tid & 63;
    const int c = l & 15;                   // q (and col) index
    const int g = l >> 4;                   // 4-lane-group

    ushort* Plw = Pl + w * 640;

    // staging coords: rows 2sp,2sp+1 ; h(m,n) = w*64 + gg*4 + m + 16n
    const int sp = tid & 15;
    const int sA = sp * 2, sB = sp * 2 + 1;
    const int gg = (tid >> 4) & 3;
    const int hbase = w * 64 + gg * 4;
    const int swzA = (sA & 7) << 3, swzB = (sB & 7) << 3;

    // Q fragments: lane holds Q[q=c][k = kk*32 + g*8 .. +7]
    const __hip_bfloat16* Qrow = Qg + ((size_t)(b * TSQ) + qt * 128 + w * 16 + c) * HD;
    short8 qf[16];
#pragma unroll
    for (int kk = 0; kk < 16; ++kk) qf[kk] = *(const short8*)(Qrow + kk * 32 + g * 8);

    f32x4 acc[32];
#pragma unroll
    for (int j = 0; j < 32; ++j) acc[j] = (f32x4){0.f, 0.f, 0.f, 0.f};
    float mrow = -1e30f, lrow = 0.f;

    const __hip_bfloat16* Kb = Kg + (size_t)(b * TSQ) * HD;

    bf4 r0[4], r1[4];
    // prologue: load tile 0
#pragma unroll
    for (int n = 0; n < 4; ++n) {
        r0[n] = *(const bf4*)(Kb + (size_t)sA * HD + hbase + n * 16);
        r1[n] = *(const bf4*)(Kb + (size_t)sB * HD + hbase + n * 16);
    }

    for (int it = 0; it < 64; ++it) {
        // ---- write tile `it` regs -> LDS (vmcnt waits auto-inserted on reg deps)
#pragma unroll
        for (int n = 0; n < 4; ++n) {
            *(bf4*)&Kl[sA * 512 + ((hbase + n * 16) ^ swzA)] = r0[n];
            *(bf4*)&Kl[sB * 512 + ((hbase + n * 16) ^ swzB)] = r1[n];
        }
#pragma unroll
        for (int n = 0; n < 4; ++n)
#pragma unroll
            for (int m = 0; m < 4; ++m) {
                int h = hbase + n * 16 + m;
                uint v = (uint)(ushort)r0[n][m] | ((uint)(ushort)r1[n][m] << 16);
                *(uint*)&Vt[h * 40 + sA] = v;
            }
        // ---- issue next tile's loads (in flight across barrier, under compute)
        if (it + 1 < 64) {
            const __hip_bfloat16* src = Kb + (size_t)((it + 1) * 32) * HD;
#pragma unroll
            for (int n = 0; n < 4; ++n) {
                r0[n] = *(const bf4*)(src + (size_t)sA * HD + hbase + n * 16);
                r1[n] = *(const bf4*)(src + (size_t)sB * HD + hbase + n * 16);
            }
        }
        asm volatile("s_waitcnt lgkmcnt(0)" ::: "memory");
        __builtin_amdgcn_s_barrier();

        // ---- QK^T (swapped): S^T = K . Q^T
        f32x4 sv[2];
        __builtin_amdgcn_s_setprio(1);
#pragma unroll
        for (int st = 0; st < 2; ++st) {
            f32x4 s_ = (f32x4){0.f, 0.f, 0.f, 0.f};
            const int srow = st * 16 + c;
            const int swz = (srow & 7) << 3;
            const ushort* kp = Kl + srow * 512;
#pragma unroll
            for (int kk = 0; kk < 16; ++kk) {
                short8 kf = *(const short8*)(kp + ((kk * 32 + g * 8) ^ swz));
                s_ = __builtin_amdgcn_mfma_f32_16x16x32_bf16(kf, qf[kk], s_, 0, 0, 0);
            }
            sv[st] = s_;
        }
        __builtin_amdgcn_s_setprio(0);

        // ---- online softmax, defer-max (lane owns q=c; s = st*16 + g*4 + r)
        float pv[8];
        float tmax = -1e30f;
#pragma unroll
        for (int st = 0; st < 2; ++st)
#pragma unroll
            for (int r = 0; r < 4; ++r) {
                float x = sv[st][r] * SCALE;
                pv[st * 4 + r] = x;
                tmax = fmaxf(tmax, x);
            }
        tmax = fmaxf(tmax, __shfl_xor(tmax, 16, 64));
        tmax = fmaxf(tmax, __shfl_xor(tmax, 32, 64));
        if (__all(tmax <= mrow + 8.0f)) {
            float tsum = 0.f;
#pragma unroll
            for (int i = 0; i < 8; ++i) { pv[i] = __expf(pv[i] - mrow); tsum += pv[i]; }
            tsum += __shfl_xor(tsum, 16, 64);
            tsum += __shfl_xor(tsum, 32, 64);
            lrow += tsum;
        } else {
            float mnew = fmaxf(mrow, tmax);
            float alpha = __expf(mrow - mnew);
            float tsum = 0.f;
#pragma unroll
            for (int i = 0; i < 8; ++i) { pv[i] = __expf(pv[i] - mnew); tsum += pv[i]; }
            tsum += __shfl_xor(tsum, 16, 64);
            tsum += __shfl_xor(tsum, 32, 64);
            lrow = lrow * alpha + tsum;
            mrow = mnew;
#pragma unroll
            for (int r = 0; r < 4; ++r) {
                float ar = __shfl(alpha, g * 4 + r, 64);
#pragma unroll
                for (int j = 0; j < 32; ++j) acc[j][r] *= ar;
            }
        }

        // ---- P (bf16 pairs) to per-wave LDS
#pragma unroll
        for (int st = 0; st < 2; ++st)
#pragma unroll
            for (int pp = 0; pp < 2; ++pp) {
                int s = st * 16 + g * 4 + pp * 2;
                uint v = (uint)(ushort)f2bf(pv[st * 4 + pp * 2]) |
                         ((uint)(ushort)f2bf(pv[st * 4 + pp * 2 + 1]) << 16);
                *(uint*)&Plw[c * 40 + s] = v;
            }

        // ---- PV: A = P-frag, B = V-frag from Vt
        short8 pa = *(const short8*)(Plw + c * 40 + g * 8);
        __builtin_amdgcn_s_setprio(1);
#pragma unroll
        for (int j = 0; j < 32; ++j) {
            short8 vb = *(const short8*)(Vt + (size_t)(j * 16 + c) * 40 + g * 8);
            acc[j] = __builtin_amdgcn_mfma_f32_16x16x32_bf16(pa, vb, acc[j], 0, 0, 0);
        }
        __builtin_amdgcn_s_setprio(0);
        __builtin_amdgcn_s_barrier();
    }

    // ---- epilogue
    float linv = 1.f / lrow;
    float* orow = out + ((size_t)(b * TSQ) + qt * 128 + w * 16) * 1024 + (pass ? HD : 0);
#pragma unroll
    for (int r = 0; r < 4; ++r) {
        float inv = __shfl(linv, g * 4 + r, 64);
#pragma unroll
        for (int j = 0; j < 32; ++j)
            orow[(size_t)(g * 4 + r) * 1024 + j * 16 + c] = acc[j][r] * inv;
    }
}

extern "C" void kernel_launch(void* const* d_in, const int* in_sizes, int n_in,
                              void* d_out, int out_size, void* d_ws, size_t ws_size,
                              hipStream_t stream) {
    const float* time_features = (const float*)d_in[0];
    const float* spec_features = (const float*)d_in[1];
    const float* conv_w = (const float*)d_in[2];
    const float* conv_b = (const float*)d_in[3];
    const float* time_w = (const float*)d_in[4];
    const float* time_b = (const float*)d_in[5];
    const float* spec_w = (const float*)d_in[6];
    const float* spec_b = (const float*)d_in[7];
    float* out = (float*)d_out;
    char* ws = (char*)d_ws;

    float* G  = (float*)(ws + OFFB_G);
    float* hb = (float*)(ws + OFFB_HB);
    __hip_bfloat16* HTb = (__hip_bfloat16*)(ws + OFFB_HT);
    __hip_bfloat16* HSb = (__hip_bfloat16*)(ws + OFFB_HS);

    (void)hipFuncSetAttribute((const void*)k_flash, hipFuncAttributeMaxDynamicSharedMemorySize, SMEM_FLASH);

    k_G<<<dim3(1024), 256, 0, stream>>>(conv_w, time_w, G);
    k_hbias<<<dim3(2), 256, 0, stream>>>(conv_b, time_w, time_b, hb);
    k_htime<<<dim3(128, 8, 2), 256, 0, stream>>>(time_features, G, hb, HTb);
    k_hspec<<<dim3(256, 8), 256, 0, stream>>>(spec_features, spec_w, spec_b, HSb);
    k_flash<<<dim3(128, 2), 512, SMEM_FLASH, stream>>>(HTb, HSb, out);
}

// Round 5
// 1356.768 us; speedup vs baseline: 1.0190x; 1.0190x over previous
//
#include <hip/hip_runtime.h>
#include <hip/hip_bf16.h>
#include <math.h>

typedef __attribute__((ext_vector_type(8))) short short8;   // 8 bf16 = 16B
typedef __attribute__((ext_vector_type(4))) short bf4;      // 4 bf16 = 8B
typedef __attribute__((ext_vector_type(4))) float f32x4;

#define BN   8
#define TSQ  2048
#define HD   512
#define TDIM 256
#define SDIM 192
#define SCALE 0.04419417382415922f

// ws layout (bytes)
#define OFFB_G   0
#define OFFB_HB  2097152
#define OFFB_HT  4194304
#define OFFB_HS  20971520

static __device__ __forceinline__ short f2bf(float f) {
    __hip_bfloat16 h = __float2bfloat16(f);
    return *(short*)&h;
}

// ---------------- G precompute: G[k][ci][h] = sum_co conv_w[ci,co,k]*time_w[co,h]
__global__ void k_G(const float* __restrict__ conv_w, const float* __restrict__ time_w,
                    float* __restrict__ G) {
    const int ci = blockIdx.x & 255;
    const int kk = blockIdx.x >> 8;
    const int tid = threadIdx.x;
    __shared__ float cw[256];
    cw[tid] = conv_w[(ci * 256 + tid) * 4 + kk];
    __syncthreads();
    float a0 = 0.f, a1 = 0.f;
    for (int co = 0; co < 256; ++co) {
        float w = cw[co];
        a0 += w * time_w[co * HD + tid];
        a1 += w * time_w[co * HD + tid + 256];
    }
    G[((kk * 256) + ci) * HD + tid] = a0;
    G[((kk * 256) + ci) * HD + tid + 256] = a1;
}

__global__ void k_hbias(const float* __restrict__ conv_b, const float* __restrict__ time_w,
                        const float* __restrict__ time_b, float* __restrict__ hb) {
    const int h = blockIdx.x * 256 + threadIdx.x;
    float a = time_b[h];
    for (int co = 0; co < 256; ++co) a += conv_b[co] * time_w[co * HD + h];
    hb[h] = a;
}

// ---------------- H_time GEMM (fused convT + linear) -> bf16
__global__ void k_htime(const float* __restrict__ X, const float* __restrict__ G,
                        const float* __restrict__ hb, __hip_bfloat16* __restrict__ HT) {
    const int z  = blockIdx.z;
    const int tid = threadIdx.x;
    __shared__ float As[64][21];
    __shared__ float Bs[16][68];

    const int ridx0 = blockIdx.x * 64;
    const int b  = ridx0 >> 10;
    const int m0 = ridx0 & 1023;
    const int col0 = blockIdx.y * 64;
    const int ga = z ? 2 : 1;
    const int gb = z ? 0 : 3;
    const int dm = z ? 1 : -1;

    const int lr = tid >> 2;
    const int lc = (tid & 3) * 4;
    const int bkr = tid >> 4;
    const int bc  = (tid & 15) * 4;
    const int tr = tid >> 4, tc = tid & 15;
    const int r0 = tr * 4, c0 = tc * 4;

    float acc[4][4] = {};

    for (int kk = 0; kk < 512; kk += 16) {
        {
            int k = kk + lc;
            int m = m0 + lr;
            int mm = m, ko = k;
            bool valid = true;
            if (k >= 256) { mm = m + dm; ko = k - 256; valid = (mm >= 0) && (mm < 1024); }
            float4 v = make_float4(0.f, 0.f, 0.f, 0.f);
            if (valid) v = *(const float4*)(X + ((b << 10) + mm) * TDIM + ko);
            As[lr][lc] = v.x; As[lr][lc + 1] = v.y; As[lr][lc + 2] = v.z; As[lr][lc + 3] = v.w;
        }
        {
            int k = kk + bkr;
            const float* Bp = (k < 256) ? (G + (ga * 256 + k) * HD)
                                        : (G + (gb * 256 + (k - 256)) * HD);
            float4 v = *(const float4*)(Bp + col0 + bc);
            *(float4*)&Bs[bkr][bc] = v;
        }
        __syncthreads();
#pragma unroll
        for (int kc = 0; kc < 16; ++kc) {
            float a[4], bb[4];
#pragma unroll
            for (int i = 0; i < 4; ++i) a[i] = As[r0 + i][kc];
#pragma unroll
            for (int j = 0; j < 4; ++j) bb[j] = Bs[kc][c0 + j];
#pragma unroll
            for (int i = 0; i < 4; ++i)
#pragma unroll
                for (int j = 0; j < 4; ++j) acc[i][j] += a[i] * bb[j];
        }
        __syncthreads();
    }
#pragma unroll
    for (int i = 0; i < 4; ++i) {
        int m = m0 + r0 + i;
        int t = 2 * m + z;
        __hip_bfloat16* op = HT + ((size_t)(b * TSQ) + t) * HD + col0;
#pragma unroll
        for (int j = 0; j < 4; ++j) op[c0 + j] = __float2bfloat16(acc[i][j] + hb[col0 + c0 + j]);
    }
}

// ---------------- H_spec GEMM -> bf16
__global__ void k_hspec(const float* __restrict__ S, const float* __restrict__ spec_w,
                        const float* __restrict__ spec_b, __hip_bfloat16* __restrict__ HS) {
    const int tid = threadIdx.x;
    __shared__ float As[64][21];
    __shared__ float Bs[16][68];

    const int row0 = blockIdx.x * 64;
    const int b  = row0 >> 11;
    const int t0 = row0 & 2047;
    const int col0 = blockIdx.y * 64;

    const int jc   = tid >> 4;
    const int toff = (tid & 15) * 4;
    const int tr = tid >> 4, tc = tid & 15;
    const int r0 = tr * 4, c0 = tc * 4;

    float acc[4][4] = {};

    for (int kk = 0; kk < 192; kk += 16) {
        int j = kk + jc;
        float4 v = *(const float4*)(S + ((size_t)(b * SDIM + j)) * TSQ + t0 + toff);
        As[toff][jc] = v.x; As[toff + 1][jc] = v.y; As[toff + 2][jc] = v.z; As[toff + 3][jc] = v.w;
        float4 w = *(const float4*)(spec_w + j * HD + col0 + tc * 4);
        *(float4*)&Bs[jc][tc * 4] = w;
        __syncthreads();
#pragma unroll
        for (int kc = 0; kc < 16; ++kc) {
            float a[4], bb[4];
#pragma unroll
            for (int i = 0; i < 4; ++i) a[i] = As[r0 + i][kc];
#pragma unroll
            for (int j2 = 0; j2 < 4; ++j2) bb[j2] = Bs[kc][c0 + j2];
#pragma unroll
            for (int i = 0; i < 4; ++i)
#pragma unroll
                for (int j2 = 0; j2 < 4; ++j2) acc[i][j2] += a[i] * bb[j2];
        }
        __syncthreads();
    }
#pragma unroll
    for (int i = 0; i < 4; ++i) {
        __hip_bfloat16* op = HS + ((size_t)(b * TSQ) + t0 + r0 + i) * HD + col0;
#pragma unroll
        for (int j2 = 0; j2 < 4; ++j2) op[c0 + j2] = __float2bfloat16(acc[i][j2] + spec_b[col0 + c0 + j2]);
    }
}

// ---------------- MFMA flash attention, V == K, bf16 in, fp32 out
// Block: 512 thr (8 waves), q-tile 128 (16/wave), KVB=32, 1 block/CU.
// Pipeline: reg-staged next tile (T14), raw s_barrier (no vmcnt drain),
// defer-max softmax (THR=8), conflict-free staging layout.
// launch_bounds(512, 1): cap VGPR at 256 (R4's ",2" capped at 128 -> spill).
#define SM_K  0
#define SM_VT 32768
#define SM_P  (32768 + 40960)
#define SMEM_FLASH (32768 + 40960 + 10240)

__global__ __launch_bounds__(512, 1)
void k_flash(const __hip_bfloat16* __restrict__ HTb, const __hip_bfloat16* __restrict__ HSb,
             float* __restrict__ out) {
    extern __shared__ char smem[];
    ushort* Kl = (ushort*)(smem + SM_K);    // [32][512]: elem at s*512 + (h ^ ((s&7)<<3))
    ushort* Vt = (ushort*)(smem + SM_VT);   // [512][40]: Vt[h*40+s] = K[s][h]
    ushort* Pl = (ushort*)(smem + SM_P);    // per wave [16][40]

    const int pass = blockIdx.y;
    const __hip_bfloat16* Qg = pass ? HSb : HTb;
    const __hip_bfloat16* Kg = pass ? HTb : HSb;
    const int b  = blockIdx.x & 7;          // batch -> XCD
    const int qt = blockIdx.x >> 3;         // 0..15
    const int tid = threadIdx.x;
    const int w = tid >> 6;
    const int l = tid & 63;
    const int c = l & 15;                   // q (and col) index
    const int g = l >> 4;                   // 4-lane-group

    ushort* Plw = Pl + w * 640;

    // staging coords: rows 2sp,2sp+1 ; h(m,n) = w*64 + gg*4 + m + 16n
    const int sp = tid & 15;
    const int sA = sp * 2, sB = sp * 2 + 1;
    const int gg = (tid >> 4) & 3;
    const int hbase = w * 64 + gg * 4;
    const int swzA = (sA & 7) << 3, swzB = (sB & 7) << 3;

    // Q fragments: lane holds Q[q=c][k = kk*32 + g*8 .. +7]
    const __hip_bfloat16* Qrow = Qg + ((size_t)(b * TSQ) + qt * 128 + w * 16 + c) * HD;
    short8 qf[16];
#pragma unroll
    for (int kk = 0; kk < 16; ++kk) qf[kk] = *(const short8*)(Qrow + kk * 32 + g * 8);

    f32x4 acc[32];
#pragma unroll
    for (int j = 0; j < 32; ++j) acc[j] = (f32x4){0.f, 0.f, 0.f, 0.f};
    float mrow = -1e30f, lrow = 0.f;

    const __hip_bfloat16* Kb = Kg + (size_t)(b * TSQ) * HD;

    bf4 r0[4], r1[4];
    // prologue: load tile 0
#pragma unroll
    for (int n = 0; n < 4; ++n) {
        r0[n] = *(const bf4*)(Kb + (size_t)sA * HD + hbase + n * 16);
        r1[n] = *(const bf4*)(Kb + (size_t)sB * HD + hbase + n * 16);
    }

    for (int it = 0; it < 64; ++it) {
        // ---- write tile `it` regs -> LDS (vmcnt waits auto-inserted on reg deps)
#pragma unroll
        for (int n = 0; n < 4; ++n) {
            *(bf4*)&Kl[sA * 512 + ((hbase + n * 16) ^ swzA)] = r0[n];
            *(bf4*)&Kl[sB * 512 + ((hbase + n * 16) ^ swzB)] = r1[n];
        }
#pragma unroll
        for (int n = 0; n < 4; ++n)
#pragma unroll
            for (int m = 0; m < 4; ++m) {
                int h = hbase + n * 16 + m;
                uint v = (uint)(ushort)r0[n][m] | ((uint)(ushort)r1[n][m] << 16);
                *(uint*)&Vt[h * 40 + sA] = v;
            }
        // ---- issue next tile's loads (in flight across barrier, under compute)
        if (it + 1 < 64) {
            const __hip_bfloat16* src = Kb + (size_t)((it + 1) * 32) * HD;
#pragma unroll
            for (int n = 0; n < 4; ++n) {
                r0[n] = *(const bf4*)(src + (size_t)sA * HD + hbase + n * 16);
                r1[n] = *(const bf4*)(src + (size_t)sB * HD + hbase + n * 16);
            }
        }
        asm volatile("s_waitcnt lgkmcnt(0)" ::: "memory");
        __builtin_amdgcn_s_barrier();

        // ---- QK^T (swapped): S^T = K . Q^T
        f32x4 sv[2];
        __builtin_amdgcn_s_setprio(1);
#pragma unroll
        for (int st = 0; st < 2; ++st) {
            f32x4 s_ = (f32x4){0.f, 0.f, 0.f, 0.f};
            const int srow = st * 16 + c;
            const int swz = (srow & 7) << 3;
            const ushort* kp = Kl + srow * 512;
#pragma unroll
            for (int kk = 0; kk < 16; ++kk) {
                short8 kf = *(const short8*)(kp + ((kk * 32 + g * 8) ^ swz));
                s_ = __builtin_amdgcn_mfma_f32_16x16x32_bf16(kf, qf[kk], s_, 0, 0, 0);
            }
            sv[st] = s_;
        }
        __builtin_amdgcn_s_setprio(0);

        // ---- online softmax, defer-max (lane owns q=c; s = st*16 + g*4 + r)
        float pv[8];
        float tmax = -1e30f;
#pragma unroll
        for (int st = 0; st < 2; ++st)
#pragma unroll
            for (int r = 0; r < 4; ++r) {
                float x = sv[st][r] * SCALE;
                pv[st * 4 + r] = x;
                tmax = fmaxf(tmax, x);
            }
        tmax = fmaxf(tmax, __shfl_xor(tmax, 16, 64));
        tmax = fmaxf(tmax, __shfl_xor(tmax, 32, 64));
        if (__all(tmax <= mrow + 8.0f)) {
            float tsum = 0.f;
#pragma unroll
            for (int i = 0; i < 8; ++i) { pv[i] = __expf(pv[i] - mrow); tsum += pv[i]; }
            tsum += __shfl_xor(tsum, 16, 64);
            tsum += __shfl_xor(tsum, 32, 64);
            lrow += tsum;
        } else {
            float mnew = fmaxf(mrow, tmax);
            float alpha = __expf(mrow - mnew);
            float tsum = 0.f;
#pragma unroll
            for (int i = 0; i < 8; ++i) { pv[i] = __expf(pv[i] - mnew); tsum += pv[i]; }
            tsum += __shfl_xor(tsum, 16, 64);
            tsum += __shfl_xor(tsum, 32, 64);
            lrow = lrow * alpha + tsum;
            mrow = mnew;
#pragma unroll
            for (int r = 0; r < 4; ++r) {
                float ar = __shfl(alpha, g * 4 + r, 64);
#pragma unroll
                for (int j = 0; j < 32; ++j) acc[j][r] *= ar;
            }
        }

        // ---- P (bf16 pairs) to per-wave LDS
#pragma unroll
        for (int st = 0; st < 2; ++st)
#pragma unroll
            for (int pp = 0; pp < 2; ++pp) {
                int s = st * 16 + g * 4 + pp * 2;
                uint v = (uint)(ushort)f2bf(pv[st * 4 + pp * 2]) |
                         ((uint)(ushort)f2bf(pv[st * 4 + pp * 2 + 1]) << 16);
                *(uint*)&Plw[c * 40 + s] = v;
            }

        // ---- PV: A = P-frag, B = V-frag from Vt
        short8 pa = *(const short8*)(Plw + c * 40 + g * 8);
        __builtin_amdgcn_s_setprio(1);
#pragma unroll
        for (int j = 0; j < 32; ++j) {
            short8 vb = *(const short8*)(Vt + (size_t)(j * 16 + c) * 40 + g * 8);
            acc[j] = __builtin_amdgcn_mfma_f32_16x16x32_bf16(pa, vb, acc[j], 0, 0, 0);
        }
        __builtin_amdgcn_s_setprio(0);
        __builtin_amdgcn_s_barrier();
    }

    // ---- epilogue
    float linv = 1.f / lrow;
    float* orow = out + ((size_t)(b * TSQ) + qt * 128 + w * 16) * 1024 + (pass ? HD : 0);
#pragma unroll
    for (int r = 0; r < 4; ++r) {
        float inv = __shfl(linv, g * 4 + r, 64);
#pragma unroll
        for (int j = 0; j < 32; ++j)
            orow[(size_t)(g * 4 + r) * 1024 + j * 16 + c] = acc[j][r] * inv;
    }
}

extern "C" void kernel_launch(void* const* d_in, const int* in_sizes, int n_in,
                              void* d_out, int out_size, void* d_ws, size_t ws_size,
                              hipStream_t stream) {
    const float* time_features = (const float*)d_in[0];
    const float* spec_features = (const float*)d_in[1];
    const float* conv_w = (const float*)d_in[2];
    const float* conv_b = (const float*)d_in[3];
    const float* time_w = (const float*)d_in[4];
    const float* time_b = (const float*)d_in[5];
    const float* spec_w = (const float*)d_in[6];
    const float* spec_b = (const float*)d_in[7];
    float* out = (float*)d_out;
    char* ws = (char*)d_ws;

    float* G  = (float*)(ws + OFFB_G);
    float* hb = (float*)(ws + OFFB_HB);
    __hip_bfloat16* HTb = (__hip_bfloat16*)(ws + OFFB_HT);
    __hip_bfloat16* HSb = (__hip_bfloat16*)(ws + OFFB_HS);

    (void)hipFuncSetAttribute((const void*)k_flash, hipFuncAttributeMaxDynamicSharedMemorySize, SMEM_FLASH);

    k_G<<<dim3(1024), 256, 0, stream>>>(conv_w, time_w, G);
    k_hbias<<<dim3(2), 256, 0, stream>>>(conv_b, time_w, time_b, hb);
    k_htime<<<dim3(128, 8, 2), 256, 0, stream>>>(time_features, G, hb, HTb);
    k_hspec<<<dim3(256, 8), 256, 0, stream>>>(spec_features, spec_w, spec_b, HSb);
    k_flash<<<dim3(128, 2), 512, SMEM_FLASH, stream>>>(HTb, HSb, out);
}

// Round 8
// 1324.708 us; speedup vs baseline: 1.0437x; 1.0242x over previous
//
#include <hip/hip_runtime.h>
#include <hip/hip_bf16.h>
#include <math.h>

typedef __attribute__((ext_vector_type(8))) short short8;   // 8 bf16 = 16B
typedef __attribute__((ext_vector_type(4))) short bf4;      // 4 bf16 = 8B
typedef __attribute__((ext_vector_type(4))) float f32x4;

#define BN   8
#define TSQ  2048
#define HD   512
#define TDIM 256
#define SDIM 192
#define SCALE 0.04419417382415922f

// ws layout (bytes)
#define OFFB_G   0
#define OFFB_HB  2097152
#define OFFB_HT  4194304
#define OFFB_HS  20971520

static __device__ __forceinline__ short f2bf(float f) {
    __hip_bfloat16 h = __float2bfloat16(f);
    return *(short*)&h;
}

// ---------------- G precompute: G[k][ci][h] = sum_co conv_w[ci,co,k]*time_w[co,h]
__global__ void k_G(const float* __restrict__ conv_w, const float* __restrict__ time_w,
                    float* __restrict__ G) {
    const int ci = blockIdx.x & 255;
    const int kk = blockIdx.x >> 8;
    const int tid = threadIdx.x;
    __shared__ float cw[256];
    cw[tid] = conv_w[(ci * 256 + tid) * 4 + kk];
    __syncthreads();
    float a0 = 0.f, a1 = 0.f;
    for (int co = 0; co < 256; ++co) {
        float w = cw[co];
        a0 += w * time_w[co * HD + tid];
        a1 += w * time_w[co * HD + tid + 256];
    }
    G[((kk * 256) + ci) * HD + tid] = a0;
    G[((kk * 256) + ci) * HD + tid + 256] = a1;
}

__global__ void k_hbias(const float* __restrict__ conv_b, const float* __restrict__ time_w,
                        const float* __restrict__ time_b, float* __restrict__ hb) {
    const int h = blockIdx.x * 256 + threadIdx.x;
    float a = time_b[h];
    for (int co = 0; co < 256; ++co) a += conv_b[co] * time_w[co * HD + h];
    hb[h] = a;
}

// ---------------- H_time GEMM (fused convT + linear) -> bf16
__global__ void k_htime(const float* __restrict__ X, const float* __restrict__ G,
                        const float* __restrict__ hb, __hip_bfloat16* __restrict__ HT) {
    const int z  = blockIdx.z;
    const int tid = threadIdx.x;
    __shared__ float As[64][21];
    __shared__ float Bs[16][68];

    const int ridx0 = blockIdx.x * 64;
    const int b  = ridx0 >> 10;
    const int m0 = ridx0 & 1023;
    const int col0 = blockIdx.y * 64;
    const int ga = z ? 2 : 1;
    const int gb = z ? 0 : 3;
    const int dm = z ? 1 : -1;

    const int lr = tid >> 2;
    const int lc = (tid & 3) * 4;
    const int bkr = tid >> 4;
    const int bc  = (tid & 15) * 4;
    const int tr = tid >> 4, tc = tid & 15;
    const int r0 = tr * 4, c0 = tc * 4;

    float acc[4][4] = {};

    for (int kk = 0; kk < 512; kk += 16) {
        {
            int k = kk + lc;
            int m = m0 + lr;
            int mm = m, ko = k;
            bool valid = true;
            if (k >= 256) { mm = m + dm; ko = k - 256; valid = (mm >= 0) && (mm < 1024); }
            float4 v = make_float4(0.f, 0.f, 0.f, 0.f);
            if (valid) v = *(const float4*)(X + ((b << 10) + mm) * TDIM + ko);
            As[lr][lc] = v.x; As[lr][lc + 1] = v.y; As[lr][lc + 2] = v.z; As[lr][lc + 3] = v.w;
        }
        {
            int k = kk + bkr;
            const float* Bp = (k < 256) ? (G + (ga * 256 + k) * HD)
                                        : (G + (gb * 256 + (k - 256)) * HD);
            float4 v = *(const float4*)(Bp + col0 + bc);
            *(float4*)&Bs[bkr][bc] = v;
        }
        __syncthreads();
#pragma unroll
        for (int kc = 0; kc < 16; ++kc) {
            float a[4], bb[4];
#pragma unroll
            for (int i = 0; i < 4; ++i) a[i] = As[r0 + i][kc];
#pragma unroll
            for (int j = 0; j < 4; ++j) bb[j] = Bs[kc][c0 + j];
#pragma unroll
            for (int i = 0; i < 4; ++i)
#pragma unroll
                for (int j = 0; j < 4; ++j) acc[i][j] += a[i] * bb[j];
        }
        __syncthreads();
    }
#pragma unroll
    for (int i = 0; i < 4; ++i) {
        int m = m0 + r0 + i;
        int t = 2 * m + z;
        __hip_bfloat16* op = HT + ((size_t)(b * TSQ) + t) * HD + col0;
#pragma unroll
        for (int j = 0; j < 4; ++j) op[c0 + j] = __float2bfloat16(acc[i][j] + hb[col0 + c0 + j]);
    }
}

// ---------------- H_spec GEMM -> bf16
__global__ void k_hspec(const float* __restrict__ S, const float* __restrict__ spec_w,
                        const float* __restrict__ spec_b, __hip_bfloat16* __restrict__ HS) {
    const int tid = threadIdx.x;
    __shared__ float As[64][21];
    __shared__ float Bs[16][68];

    const int row0 = blockIdx.x * 64;
    const int b  = row0 >> 11;
    const int t0 = row0 & 2047;
    const int col0 = blockIdx.y * 64;

    const int jc   = tid >> 4;
    const int toff = (tid & 15) * 4;
    const int tr = tid >> 4, tc = tid & 15;
    const int r0 = tr * 4, c0 = tc * 4;

    float acc[4][4] = {};

    for (int kk = 0; kk < 192; kk += 16) {
        int j = kk + jc;
        float4 v = *(const float4*)(S + ((size_t)(b * SDIM + j)) * TSQ + t0 + toff);
        As[toff][jc] = v.x; As[toff + 1][jc] = v.y; As[toff + 2][jc] = v.z; As[toff + 3][jc] = v.w;
        float4 w = *(const float4*)(spec_w + j * HD + col0 + tc * 4);
        *(float4*)&Bs[jc][tc * 4] = w;
        __syncthreads();
#pragma unroll
        for (int kc = 0; kc < 16; ++kc) {
            float a[4], bb[4];
#pragma unroll
            for (int i = 0; i < 4; ++i) a[i] = As[r0 + i][kc];
#pragma unroll
            for (int j2 = 0; j2 < 4; ++j2) bb[j2] = Bs[kc][c0 + j2];
#pragma unroll
            for (int i = 0; i < 4; ++i)
#pragma unroll
                for (int j2 = 0; j2 < 4; ++j2) acc[i][j2] += a[i] * bb[j2];
        }
        __syncthreads();
    }
#pragma unroll
    for (int i = 0; i < 4; ++i) {
        __hip_bfloat16* op = HS + ((size_t)(b * TSQ) + t0 + r0 + i) * HD + col0;
#pragma unroll
        for (int j2 = 0; j2 < 4; ++j2) op[c0 + j2] = __float2bfloat16(acc[i][j2] + spec_b[col0 + c0 + j2]);
    }
}

// ---------------- MFMA flash attention, V == K, bf16 in, fp32 out
// Block: 512 thr (8 waves), q-tile 128 (16/wave), KVB=32, 1 block/CU.
// amdgpu_waves_per_eu(2): min 2 waves/EU -> VGPR budget 256/wave (R4/R5
// allocated only 128 arch VGPRs -> qf spilled, 2.4GB/launch spill traffic).
#define SM_K  0
#define SM_VT 32768
#define SM_P  (32768 + 40960)
#define SMEM_FLASH (32768 + 40960 + 10240)

__global__ __launch_bounds__(512)
__attribute__((amdgpu_waves_per_eu(2)))
void k_flash(const __hip_bfloat16* __restrict__ HTb, const __hip_bfloat16* __restrict__ HSb,
             float* __restrict__ out) {
    extern __shared__ char smem[];
    ushort* Kl = (ushort*)(smem + SM_K);    // [32][512]: elem at s*512 + (h ^ ((s&7)<<3))
    ushort* Vt = (ushort*)(smem + SM_VT);   // [512][40]: Vt[h*40+s] = K[s][h]
    ushort* Pl = (ushort*)(smem + SM_P);    // per wave [16][40]

    const int pass = blockIdx.y;
    const __hip_bfloat16* Qg = pass ? HSb : HTb;
    const __hip_bfloat16* Kg = pass ? HTb : HSb;
    const int b  = blockIdx.x & 7;          // batch -> XCD
    const int qt = blockIdx.x >> 3;         // 0..15
    const int tid = threadIdx.x;
    const int w = tid >> 6;
    const int l = tid & 63;
    const int c = l & 15;                   // q (and col) index
    const int g = l >> 4;                   // 4-lane-group

    ushort* Plw = Pl + w * 640;

    // staging coords: rows 2sp,2sp+1 ; h(m,n) = w*64 + gg*4 + m + 16n
    const int sp = tid & 15;
    const int sA = sp * 2, sB = sp * 2 + 1;
    const int gg = (tid >> 4) & 3;
    const int hbase = w * 64 + gg * 4;
    const int swzA = (sA & 7) << 3, swzB = (sB & 7) << 3;

    // Q fragments: lane holds Q[q=c][k = kk*32 + g*8 .. +7]
    const __hip_bfloat16* Qrow = Qg + ((size_t)(b * TSQ) + qt * 128 + w * 16 + c) * HD;
    short8 qf[16];
#pragma unroll
    for (int kk = 0; kk < 16; ++kk) qf[kk] = *(const short8*)(Qrow + kk * 32 + g * 8);

    f32x4 acc[32];
#pragma unroll
    for (int j = 0; j < 32; ++j) acc[j] = (f32x4){0.f, 0.f, 0.f, 0.f};
    float mrow = -1e30f, lrow = 0.f;

    const __hip_bfloat16* Kb = Kg + (size_t)(b * TSQ) * HD;

    bf4 r0[4], r1[4];
    // prologue: load tile 0
#pragma unroll
    for (int n = 0; n < 4; ++n) {
        r0[n] = *(const bf4*)(Kb + (size_t)sA * HD + hbase + n * 16);
        r1[n] = *(const bf4*)(Kb + (size_t)sB * HD + hbase + n * 16);
    }

    for (int it = 0; it < 64; ++it) {
        // ---- write tile `it` regs -> LDS (vmcnt waits auto-inserted on reg deps)
#pragma unroll
        for (int n = 0; n < 4; ++n) {
            *(bf4*)&Kl[sA * 512 + ((hbase + n * 16) ^ swzA)] = r0[n];
            *(bf4*)&Kl[sB * 512 + ((hbase + n * 16) ^ swzB)] = r1[n];
        }
#pragma unroll
        for (int n = 0; n < 4; ++n)
#pragma unroll
            for (int m = 0; m < 4; ++m) {
                int h = hbase + n * 16 + m;
                uint v = (uint)(ushort)r0[n][m] | ((uint)(ushort)r1[n][m] << 16);
                *(uint*)&Vt[h * 40 + sA] = v;
            }
        // ---- issue next tile's loads (in flight across barrier, under compute)
        if (it + 1 < 64) {
            const __hip_bfloat16* src = Kb + (size_t)((it + 1) * 32) * HD;
#pragma unroll
            for (int n = 0; n < 4; ++n) {
                r0[n] = *(const bf4*)(src + (size_t)sA * HD + hbase + n * 16);
                r1[n] = *(const bf4*)(src + (size_t)sB * HD + hbase + n * 16);
            }
        }
        asm volatile("s_waitcnt lgkmcnt(0)" ::: "memory");
        __builtin_amdgcn_s_barrier();

        // ---- QK^T (swapped): S^T = K . Q^T
        f32x4 sv[2];
        __builtin_amdgcn_s_setprio(1);
#pragma unroll
        for (int st = 0; st < 2; ++st) {
            f32x4 s_ = (f32x4){0.f, 0.f, 0.f, 0.f};
            const int srow = st * 16 + c;
            const int swz = (srow & 7) << 3;
            const ushort* kp = Kl + srow * 512;
#pragma unroll
            for (int kk = 0; kk < 16; ++kk) {
                short8 kf = *(const short8*)(kp + ((kk * 32 + g * 8) ^ swz));
                s_ = __builtin_amdgcn_mfma_f32_16x16x32_bf16(kf, qf[kk], s_, 0, 0, 0);
            }
            sv[st] = s_;
        }
        __builtin_amdgcn_s_setprio(0);

        // ---- online softmax, defer-max; exp in place in sv (register diet)
        float tmax = -1e30f;
#pragma unroll
        for (int st = 0; st < 2; ++st)
#pragma unroll
            for (int r = 0; r < 4; ++r) {
                float x = sv[st][r] * SCALE;
                sv[st][r] = x;
                tmax = fmaxf(tmax, x);
            }
        tmax = fmaxf(tmax, __shfl_xor(tmax, 16, 64));
        tmax = fmaxf(tmax, __shfl_xor(tmax, 32, 64));
        if (__all(tmax <= mrow + 8.0f)) {
            float tsum = 0.f;
#pragma unroll
            for (int st = 0; st < 2; ++st)
#pragma unroll
                for (int r = 0; r < 4; ++r) { float e = __expf(sv[st][r] - mrow); sv[st][r] = e; tsum += e; }
            tsum += __shfl_xor(tsum, 16, 64);
            tsum += __shfl_xor(tsum, 32, 64);
            lrow += tsum;
        } else {
            float mnew = fmaxf(mrow, tmax);
            float alpha = __expf(mrow - mnew);
            float tsum = 0.f;
#pragma unroll
            for (int st = 0; st < 2; ++st)
#pragma unroll
                for (int r = 0; r < 4; ++r) { float e = __expf(sv[st][r] - mnew); sv[st][r] = e; tsum += e; }
            tsum += __shfl_xor(tsum, 16, 64);
            tsum += __shfl_xor(tsum, 32, 64);
            lrow = lrow * alpha + tsum;
            mrow = mnew;
#pragma unroll
            for (int r = 0; r < 4; ++r) {
                float ar = __shfl(alpha, g * 4 + r, 64);
#pragma unroll
                for (int j = 0; j < 32; ++j) acc[j][r] *= ar;
            }
        }

        // ---- P (bf16 pairs) to per-wave LDS
#pragma unroll
        for (int st = 0; st < 2; ++st)
#pragma unroll
            for (int pp = 0; pp < 2; ++pp) {
                int s = st * 16 + g * 4 + pp * 2;
                uint v = (uint)(ushort)f2bf(sv[st][pp * 2]) |
                         ((uint)(ushort)f2bf(sv[st][pp * 2 + 1]) << 16);
                *(uint*)&Plw[c * 40 + s] = v;
            }

        // ---- PV: A = P-frag, B = V-frag from Vt
        short8 pa = *(const short8*)(Plw + c * 40 + g * 8);
        __builtin_amdgcn_s_setprio(1);
#pragma unroll
        for (int j = 0; j < 32; ++j) {
            short8 vb = *(const short8*)(Vt + (size_t)(j * 16 + c) * 40 + g * 8);
            acc[j] = __builtin_amdgcn_mfma_f32_16x16x32_bf16(pa, vb, acc[j], 0, 0, 0);
        }
        __builtin_amdgcn_s_setprio(0);
        asm volatile("" ::: "memory");
        __builtin_amdgcn_s_barrier();
    }

    // ---- epilogue
    float linv = 1.f / lrow;
    float* orow = out + ((size_t)(b * TSQ) + qt * 128 + w * 16) * 1024 + (pass ? HD : 0);
#pragma unroll
    for (int r = 0; r < 4; ++r) {
        float inv = __shfl(linv, g * 4 + r, 64);
#pragma unroll
        for (int j = 0; j < 32; ++j)
            orow[(size_t)(g * 4 + r) * 1024 + j * 16 + c] = acc[j][r] * inv;
    }
}

extern "C" void kernel_launch(void* const* d_in, const int* in_sizes, int n_in,
                              void* d_out, int out_size, void* d_ws, size_t ws_size,
                              hipStream_t stream) {
    const float* time_features = (const float*)d_in[0];
    const float* spec_features = (const float*)d_in[1];
    const float* conv_w = (const float*)d_in[2];
    const float* conv_b = (const float*)d_in[3];
    const float* time_w = (const float*)d_in[4];
    const float* time_b = (const float*)d_in[5];
    const float* spec_w = (const float*)d_in[6];
    const float* spec_b = (const float*)d_in[7];
    float* out = (float*)d_out;
    char* ws = (char*)d_ws;

    float* G  = (float*)(ws + OFFB_G);
    float* hb = (float*)(ws + OFFB_HB);
    __hip_bfloat16* HTb = (__hip_bfloat16*)(ws + OFFB_HT);
    __hip_bfloat16* HSb = (__hip_bfloat16*)(ws + OFFB_HS);

    (void)hipFuncSetAttribute((const void*)k_flash, hipFuncAttributeMaxDynamicSharedMemorySize, SMEM_FLASH);

    k_G<<<dim3(1024), 256, 0, stream>>>(conv_w, time_w, G);
    k_hbias<<<dim3(2), 256, 0, stream>>>(conv_b, time_w, time_b, hb);
    k_htime<<<dim3(128, 8, 2), 256, 0, stream>>>(time_features, G, hb, HTb);
    k_hspec<<<dim3(256, 8), 256, 0, stream>>>(spec_features, spec_w, spec_b, HSb);
    k_flash<<<dim3(128, 2), 512, SMEM_FLASH, stream>>>(HTb, HSb, out);
}

// Round 9
// 796.885 us; speedup vs baseline: 1.7350x; 1.6624x over previous
//
#include <hip/hip_runtime.h>
#include <hip/hip_bf16.h>
#include <math.h>

typedef __attribute__((ext_vector_type(8))) short short8;   // 8 bf16 = 16B
typedef __attribute__((ext_vector_type(4))) short bf4;      // 4 bf16 = 8B
typedef __attribute__((ext_vector_type(4))) float f32x4;

#define BN   8
#define TSQ  2048
#define HD   512
#define TDIM 256
#define SDIM 192
#define SCALE 0.04419417382415922f

// ws layout (bytes)
#define OFFB_G   0
#define OFFB_HB  2097152
#define OFFB_HT  4194304
#define OFFB_HS  20971520

static __device__ __forceinline__ short f2bf(float f) {
    __hip_bfloat16 h = __float2bfloat16(f);
    return *(short*)&h;
}

// ---------------- G precompute: G[k][ci][h] = sum_co conv_w[ci,co,k]*time_w[co,h]
__global__ void k_G(const float* __restrict__ conv_w, const float* __restrict__ time_w,
                    float* __restrict__ G) {
    const int ci = blockIdx.x & 255;
    const int kk = blockIdx.x >> 8;
    const int tid = threadIdx.x;
    __shared__ float cw[256];
    cw[tid] = conv_w[(ci * 256 + tid) * 4 + kk];
    __syncthreads();
    float a0 = 0.f, a1 = 0.f;
    for (int co = 0; co < 256; ++co) {
        float w = cw[co];
        a0 += w * time_w[co * HD + tid];
        a1 += w * time_w[co * HD + tid + 256];
    }
    G[((kk * 256) + ci) * HD + tid] = a0;
    G[((kk * 256) + ci) * HD + tid + 256] = a1;
}

__global__ void k_hbias(const float* __restrict__ conv_b, const float* __restrict__ time_w,
                        const float* __restrict__ time_b, float* __restrict__ hb) {
    const int h = blockIdx.x * 256 + threadIdx.x;
    float a = time_b[h];
    for (int co = 0; co < 256; ++co) a += conv_b[co] * time_w[co * HD + h];
    hb[h] = a;
}

// ---------------- H_time GEMM (fused convT + linear) -> bf16
__global__ void k_htime(const float* __restrict__ X, const float* __restrict__ G,
                        const float* __restrict__ hb, __hip_bfloat16* __restrict__ HT) {
    const int z  = blockIdx.z;
    const int tid = threadIdx.x;
    __shared__ float As[64][21];
    __shared__ float Bs[16][68];

    const int ridx0 = blockIdx.x * 64;
    const int b  = ridx0 >> 10;
    const int m0 = ridx0 & 1023;
    const int col0 = blockIdx.y * 64;
    const int ga = z ? 2 : 1;
    const int gb = z ? 0 : 3;
    const int dm = z ? 1 : -1;

    const int lr = tid >> 2;
    const int lc = (tid & 3) * 4;
    const int bkr = tid >> 4;
    const int bc  = (tid & 15) * 4;
    const int tr = tid >> 4, tc = tid & 15;
    const int r0 = tr * 4, c0 = tc * 4;

    float acc[4][4] = {};

    for (int kk = 0; kk < 512; kk += 16) {
        {
            int k = kk + lc;
            int m = m0 + lr;
            int mm = m, ko = k;
            bool valid = true;
            if (k >= 256) { mm = m + dm; ko = k - 256; valid = (mm >= 0) && (mm < 1024); }
            float4 v = make_float4(0.f, 0.f, 0.f, 0.f);
            if (valid) v = *(const float4*)(X + ((b << 10) + mm) * TDIM + ko);
            As[lr][lc] = v.x; As[lr][lc + 1] = v.y; As[lr][lc + 2] = v.z; As[lr][lc + 3] = v.w;
        }
        {
            int k = kk + bkr;
            const float* Bp = (k < 256) ? (G + (ga * 256 + k) * HD)
                                        : (G + (gb * 256 + (k - 256)) * HD);
            float4 v = *(const float4*)(Bp + col0 + bc);
            *(float4*)&Bs[bkr][bc] = v;
        }
        __syncthreads();
#pragma unroll
        for (int kc = 0; kc < 16; ++kc) {
            float a[4], bb[4];
#pragma unroll
            for (int i = 0; i < 4; ++i) a[i] = As[r0 + i][kc];
#pragma unroll
            for (int j = 0; j < 4; ++j) bb[j] = Bs[kc][c0 + j];
#pragma unroll
            for (int i = 0; i < 4; ++i)
#pragma unroll
                for (int j = 0; j < 4; ++j) acc[i][j] += a[i] * bb[j];
        }
        __syncthreads();
    }
#pragma unroll
    for (int i = 0; i < 4; ++i) {
        int m = m0 + r0 + i;
        int t = 2 * m + z;
        __hip_bfloat16* op = HT + ((size_t)(b * TSQ) + t) * HD + col0;
#pragma unroll
        for (int j = 0; j < 4; ++j) op[c0 + j] = __float2bfloat16(acc[i][j] + hb[col0 + c0 + j]);
    }
}

// ---------------- H_spec GEMM -> bf16
__global__ void k_hspec(const float* __restrict__ S, const float* __restrict__ spec_w,
                        const float* __restrict__ spec_b, __hip_bfloat16* __restrict__ HS) {
    const int tid = threadIdx.x;
    __shared__ float As[64][21];
    __shared__ float Bs[16][68];

    const int row0 = blockIdx.x * 64;
    const int b  = row0 >> 11;
    const int t0 = row0 & 2047;
    const int col0 = blockIdx.y * 64;

    const int jc   = tid >> 4;
    const int toff = (tid & 15) * 4;
    const int tr = tid >> 4, tc = tid & 15;
    const int r0 = tr * 4, c0 = tc * 4;

    float acc[4][4] = {};

    for (int kk = 0; kk < 192; kk += 16) {
        int j = kk + jc;
        float4 v = *(const float4*)(S + ((size_t)(b * SDIM + j)) * TSQ + t0 + toff);
        As[toff][jc] = v.x; As[toff + 1][jc] = v.y; As[toff + 2][jc] = v.z; As[toff + 3][jc] = v.w;
        float4 w = *(const float4*)(spec_w + j * HD + col0 + tc * 4);
        *(float4*)&Bs[jc][tc * 4] = w;
        __syncthreads();
#pragma unroll
        for (int kc = 0; kc < 16; ++kc) {
            float a[4], bb[4];
#pragma unroll
            for (int i = 0; i < 4; ++i) a[i] = As[r0 + i][kc];
#pragma unroll
            for (int j2 = 0; j2 < 4; ++j2) bb[j2] = Bs[kc][c0 + j2];
#pragma unroll
            for (int i = 0; i < 4; ++i)
#pragma unroll
                for (int j2 = 0; j2 < 4; ++j2) acc[i][j2] += a[i] * bb[j2];
        }
        __syncthreads();
    }
#pragma unroll
    for (int i = 0; i < 4; ++i) {
        __hip_bfloat16* op = HS + ((size_t)(b * TSQ) + t0 + r0 + i) * HD + col0;
#pragma unroll
        for (int j2 = 0; j2 < 4; ++j2) op[c0 + j2] = __float2bfloat16(acc[i][j2] + spec_b[col0 + c0 + j2]);
    }
}

// ---------------- MFMA flash attention, V == K, bf16 in, fp32 out
// h-SPLIT: each block computes 256 of the 512 output columns (blockIdx.z).
// Why: a 512-thr block caps the unified reg budget at 256/wave; full acc
// (128 AGPR) forced arch to 128 -> qf spilled (R4-R8: 2.3GB spill traffic).
// Half acc = 64 AGPR -> arch cap 192 vs ~140 demand -> no spill.
// QK^T duplicated across the h-pair (MFMA was only 4.6% util - cheap).
#define SM_K   0
#define SM_VT  32768
#define SM_P   (32768 + 20480)
#define SMEM_FLASH (32768 + 20480 + 10240)

__global__ __launch_bounds__(512)
void k_flash(const __hip_bfloat16* __restrict__ HTb, const __hip_bfloat16* __restrict__ HSb,
             float* __restrict__ out) {
    extern __shared__ char smem[];
    ushort* Kl = (ushort*)(smem + SM_K);    // [32][512]: elem at s*512 + (h ^ ((s&7)<<3))
    ushort* Vt = (ushort*)(smem + SM_VT);   // [256][40]: Vt[hh*40+s] = K[s][half*256+hh]
    ushort* Pl = (ushort*)(smem + SM_P);    // per wave [16][40]

    const int pass = blockIdx.y;
    const int half = blockIdx.z;            // h-half: 0 -> cols 0..255, 1 -> 256..511
    const __hip_bfloat16* Qg = pass ? HSb : HTb;
    const __hip_bfloat16* Kg = pass ? HTb : HSb;
    const int b  = blockIdx.x & 7;          // batch -> XCD
    const int qt = blockIdx.x >> 3;         // 0..15
    const int tid = threadIdx.x;
    const int w = tid >> 6;
    const int l = tid & 63;
    const int c = l & 15;                   // q (and col) index
    const int g = l >> 4;                   // 4-lane-group

    ushort* Plw = Pl + w * 640;

    // staging coords: rows 2sp,2sp+1 ; h(m,n) = w*64 + gg*4 + m + 16n
    const int sp = tid & 15;
    const int sA = sp * 2, sB = sp * 2 + 1;
    const int gg = (tid >> 4) & 3;
    const int hbase = w * 64 + gg * 4;
    const int swzA = (sA & 7) << 3, swzB = (sB & 7) << 3;
    const bool myVt = (w >> 2) == half;     // waves 0-3 own h<256, 4-7 own h>=256
    const int hhbase = (w & 3) * 64 + gg * 4;

    // Q fragments: lane holds Q[q=c][k = kk*32 + g*8 .. +7]
    const __hip_bfloat16* Qrow = Qg + ((size_t)(b * TSQ) + qt * 128 + w * 16 + c) * HD;
    short8 qf[16];
#pragma unroll
    for (int kk = 0; kk < 16; ++kk) qf[kk] = *(const short8*)(Qrow + kk * 32 + g * 8);

    f32x4 acc[16];
#pragma unroll
    for (int j = 0; j < 16; ++j) acc[j] = (f32x4){0.f, 0.f, 0.f, 0.f};
    float mrow = -1e30f, lrow = 0.f;

    const __hip_bfloat16* Kb = Kg + (size_t)(b * TSQ) * HD;

    bf4 r0[4], r1[4];
    // prologue: load tile 0
#pragma unroll
    for (int n = 0; n < 4; ++n) {
        r0[n] = *(const bf4*)(Kb + (size_t)sA * HD + hbase + n * 16);
        r1[n] = *(const bf4*)(Kb + (size_t)sB * HD + hbase + n * 16);
    }

    for (int it = 0; it < 64; ++it) {
        // ---- write tile `it` regs -> LDS
#pragma unroll
        for (int n = 0; n < 4; ++n) {
            *(bf4*)&Kl[sA * 512 + ((hbase + n * 16) ^ swzA)] = r0[n];
            *(bf4*)&Kl[sB * 512 + ((hbase + n * 16) ^ swzB)] = r1[n];
        }
        if (myVt) {
#pragma unroll
            for (int n = 0; n < 4; ++n)
#pragma unroll
                for (int m = 0; m < 4; ++m) {
                    int hh = hhbase + n * 16 + m;
                    uint v = (uint)(ushort)r0[n][m] | ((uint)(ushort)r1[n][m] << 16);
                    *(uint*)&Vt[hh * 40 + sA] = v;
                }
        }
        // ---- issue next tile's loads (in flight across barrier, under compute)
        if (it + 1 < 64) {
            const __hip_bfloat16* src = Kb + (size_t)((it + 1) * 32) * HD;
#pragma unroll
            for (int n = 0; n < 4; ++n) {
                r0[n] = *(const bf4*)(src + (size_t)sA * HD + hbase + n * 16);
                r1[n] = *(const bf4*)(src + (size_t)sB * HD + hbase + n * 16);
            }
        }
        asm volatile("s_waitcnt lgkmcnt(0)" ::: "memory");
        __builtin_amdgcn_s_barrier();

        // ---- QK^T (swapped): S^T = K . Q^T  (full 512-dim, duplicated per half)
        f32x4 sv[2];
        __builtin_amdgcn_s_setprio(1);
#pragma unroll
        for (int st = 0; st < 2; ++st) {
            f32x4 s_ = (f32x4){0.f, 0.f, 0.f, 0.f};
            const int srow = st * 16 + c;
            const int swz = (srow & 7) << 3;
            const ushort* kp = Kl + srow * 512;
#pragma unroll
            for (int kk = 0; kk < 16; ++kk) {
                short8 kf = *(const short8*)(kp + ((kk * 32 + g * 8) ^ swz));
                s_ = __builtin_amdgcn_mfma_f32_16x16x32_bf16(kf, qf[kk], s_, 0, 0, 0);
            }
            sv[st] = s_;
        }
        __builtin_amdgcn_s_setprio(0);

        // ---- online softmax, defer-max (lane owns q=c; s = st*16 + g*4 + r)
        float tmax = -1e30f;
#pragma unroll
        for (int st = 0; st < 2; ++st)
#pragma unroll
            for (int r = 0; r < 4; ++r) {
                float x = sv[st][r] * SCALE;
                sv[st][r] = x;
                tmax = fmaxf(tmax, x);
            }
        tmax = fmaxf(tmax, __shfl_xor(tmax, 16, 64));
        tmax = fmaxf(tmax, __shfl_xor(tmax, 32, 64));
        if (__all(tmax <= mrow + 8.0f)) {
            float tsum = 0.f;
#pragma unroll
            for (int st = 0; st < 2; ++st)
#pragma unroll
                for (int r = 0; r < 4; ++r) { float e = __expf(sv[st][r] - mrow); sv[st][r] = e; tsum += e; }
            tsum += __shfl_xor(tsum, 16, 64);
            tsum += __shfl_xor(tsum, 32, 64);
            lrow += tsum;
        } else {
            float mnew = fmaxf(mrow, tmax);
            float alpha = __expf(mrow - mnew);
            float tsum = 0.f;
#pragma unroll
            for (int st = 0; st < 2; ++st)
#pragma unroll
                for (int r = 0; r < 4; ++r) { float e = __expf(sv[st][r] - mnew); sv[st][r] = e; tsum += e; }
            tsum += __shfl_xor(tsum, 16, 64);
            tsum += __shfl_xor(tsum, 32, 64);
            lrow = lrow * alpha + tsum;
            mrow = mnew;
#pragma unroll
            for (int r = 0; r < 4; ++r) {
                float ar = __shfl(alpha, g * 4 + r, 64);
#pragma unroll
                for (int j = 0; j < 16; ++j) acc[j][r] *= ar;
            }
        }

        // ---- P (bf16 pairs) to per-wave LDS
#pragma unroll
        for (int st = 0; st < 2; ++st)
#pragma unroll
            for (int pp = 0; pp < 2; ++pp) {
                int s = st * 16 + g * 4 + pp * 2;
                uint v = (uint)(ushort)f2bf(sv[st][pp * 2]) |
                         ((uint)(ushort)f2bf(sv[st][pp * 2 + 1]) << 16);
                *(uint*)&Plw[c * 40 + s] = v;
            }

        // ---- PV over this block's h-half: A = P-frag, B = V-frag from Vt
        short8 pa = *(const short8*)(Plw + c * 40 + g * 8);
        __builtin_amdgcn_s_setprio(1);
#pragma unroll
        for (int j = 0; j < 16; ++j) {
            short8 vb = *(const short8*)(Vt + (size_t)(j * 16 + c) * 40 + g * 8);
            acc[j] = __builtin_amdgcn_mfma_f32_16x16x32_bf16(pa, vb, acc[j], 0, 0, 0);
        }
        __builtin_amdgcn_s_setprio(0);
        asm volatile("" ::: "memory");
        __builtin_amdgcn_s_barrier();
    }

    // ---- epilogue: divide by l per q-row, store this half's 256 fp32 cols
    float linv = 1.f / lrow;
    float* orow = out + ((size_t)(b * TSQ) + qt * 128 + w * 16) * 1024 + pass * HD + half * 256;
#pragma unroll
    for (int r = 0; r < 4; ++r) {
        float inv = __shfl(linv, g * 4 + r, 64);
#pragma unroll
        for (int j = 0; j < 16; ++j)
            orow[(size_t)(g * 4 + r) * 1024 + j * 16 + c] = acc[j][r] * inv;
    }
}

extern "C" void kernel_launch(void* const* d_in, const int* in_sizes, int n_in,
                              void* d_out, int out_size, void* d_ws, size_t ws_size,
                              hipStream_t stream) {
    const float* time_features = (const float*)d_in[0];
    const float* spec_features = (const float*)d_in[1];
    const float* conv_w = (const float*)d_in[2];
    const float* conv_b = (const float*)d_in[3];
    const float* time_w = (const float*)d_in[4];
    const float* time_b = (const float*)d_in[5];
    const float* spec_w = (const float*)d_in[6];
    const float* spec_b = (const float*)d_in[7];
    float* out = (float*)d_out;
    char* ws = (char*)d_ws;

    float* G  = (float*)(ws + OFFB_G);
    float* hb = (float*)(ws + OFFB_HB);
    __hip_bfloat16* HTb = (__hip_bfloat16*)(ws + OFFB_HT);
    __hip_bfloat16* HSb = (__hip_bfloat16*)(ws + OFFB_HS);

    (void)hipFuncSetAttribute((const void*)k_flash, hipFuncAttributeMaxDynamicSharedMemorySize, SMEM_FLASH);

    k_G<<<dim3(1024), 256, 0, stream>>>(conv_w, time_w, G);
    k_hbias<<<dim3(2), 256, 0, stream>>>(conv_b, time_w, time_b, hb);
    k_htime<<<dim3(128, 8, 2), 256, 0, stream>>>(time_features, G, hb, HTb);
    k_hspec<<<dim3(256, 8), 256, 0, stream>>>(spec_features, spec_w, spec_b, HSb);
    k_flash<<<dim3(128, 2, 2), 512, SMEM_FLASH, stream>>>(HTb, HSb, out);
}

// Round 10
// 743.843 us; speedup vs baseline: 1.8587x; 1.0713x over previous
//
#include <hip/hip_runtime.h>
#include <hip/hip_bf16.h>
#include <math.h>

typedef __attribute__((ext_vector_type(8))) short short8;   // 8 bf16 = 16B
typedef __attribute__((ext_vector_type(4))) short bf4;      // 4 bf16 = 8B
typedef __attribute__((ext_vector_type(4))) float f32x4;

#define BN   8
#define TSQ  2048
#define HD   512
#define TDIM 256
#define SDIM 192
#define SCALE 0.04419417382415922f

// ws layout (bytes)
#define OFFB_G   0
#define OFFB_HB  2097152
#define OFFB_HT  4194304
#define OFFB_HS  20971520

static __device__ __forceinline__ short f2bf(float f) {
    __hip_bfloat16 h = __float2bfloat16(f);
    return *(short*)&h;
}

// ---------------- G precompute: G[k][ci][h] = sum_co conv_w[ci,co,k]*time_w[co,h]
__global__ void k_G(const float* __restrict__ conv_w, const float* __restrict__ time_w,
                    float* __restrict__ G) {
    const int ci = blockIdx.x & 255;
    const int kk = blockIdx.x >> 8;
    const int tid = threadIdx.x;
    __shared__ float cw[256];
    cw[tid] = conv_w[(ci * 256 + tid) * 4 + kk];
    __syncthreads();
    float a0 = 0.f, a1 = 0.f;
    for (int co = 0; co < 256; ++co) {
        float w = cw[co];
        a0 += w * time_w[co * HD + tid];
        a1 += w * time_w[co * HD + tid + 256];
    }
    G[((kk * 256) + ci) * HD + tid] = a0;
    G[((kk * 256) + ci) * HD + tid + 256] = a1;
}

__global__ void k_hbias(const float* __restrict__ conv_b, const float* __restrict__ time_w,
                        const float* __restrict__ time_b, float* __restrict__ hb) {
    const int h = blockIdx.x * 256 + threadIdx.x;
    float a = time_b[h];
    for (int co = 0; co < 256; ++co) a += conv_b[co] * time_w[co * HD + h];
    hb[h] = a;
}

// ---------------- H_time GEMM (fused convT + linear) -> bf16
__global__ void k_htime(const float* __restrict__ X, const float* __restrict__ G,
                        const float* __restrict__ hb, __hip_bfloat16* __restrict__ HT) {
    const int z  = blockIdx.z;
    const int tid = threadIdx.x;
    __shared__ float As[64][21];
    __shared__ float Bs[16][68];

    const int ridx0 = blockIdx.x * 64;
    const int b  = ridx0 >> 10;
    const int m0 = ridx0 & 1023;
    const int col0 = blockIdx.y * 64;
    const int ga = z ? 2 : 1;
    const int gb = z ? 0 : 3;
    const int dm = z ? 1 : -1;

    const int lr = tid >> 2;
    const int lc = (tid & 3) * 4;
    const int bkr = tid >> 4;
    const int bc  = (tid & 15) * 4;
    const int tr = tid >> 4, tc = tid & 15;
    const int r0 = tr * 4, c0 = tc * 4;

    float acc[4][4] = {};

    for (int kk = 0; kk < 512; kk += 16) {
        {
            int k = kk + lc;
            int m = m0 + lr;
            int mm = m, ko = k;
            bool valid = true;
            if (k >= 256) { mm = m + dm; ko = k - 256; valid = (mm >= 0) && (mm < 1024); }
            float4 v = make_float4(0.f, 0.f, 0.f, 0.f);
            if (valid) v = *(const float4*)(X + ((b << 10) + mm) * TDIM + ko);
            As[lr][lc] = v.x; As[lr][lc + 1] = v.y; As[lr][lc + 2] = v.z; As[lr][lc + 3] = v.w;
        }
        {
            int k = kk + bkr;
            const float* Bp = (k < 256) ? (G + (ga * 256 + k) * HD)
                                        : (G + (gb * 256 + (k - 256)) * HD);
            float4 v = *(const float4*)(Bp + col0 + bc);
            *(float4*)&Bs[bkr][bc] = v;
        }
        __syncthreads();
#pragma unroll
        for (int kc = 0; kc < 16; ++kc) {
            float a[4], bb[4];
#pragma unroll
            for (int i = 0; i < 4; ++i) a[i] = As[r0 + i][kc];
#pragma unroll
            for (int j = 0; j < 4; ++j) bb[j] = Bs[kc][c0 + j];
#pragma unroll
            for (int i = 0; i < 4; ++i)
#pragma unroll
                for (int j = 0; j < 4; ++j) acc[i][j] += a[i] * bb[j];
        }
        __syncthreads();
    }
#pragma unroll
    for (int i = 0; i < 4; ++i) {
        int m = m0 + r0 + i;
        int t = 2 * m + z;
        __hip_bfloat16* op = HT + ((size_t)(b * TSQ) + t) * HD + col0;
#pragma unroll
        for (int j = 0; j < 4; ++j) op[c0 + j] = __float2bfloat16(acc[i][j] + hb[col0 + c0 + j]);
    }
}

// ---------------- H_spec GEMM -> bf16
__global__ void k_hspec(const float* __restrict__ S, const float* __restrict__ spec_w,
                        const float* __restrict__ spec_b, __hip_bfloat16* __restrict__ HS) {
    const int tid = threadIdx.x;
    __shared__ float As[64][21];
    __shared__ float Bs[16][68];

    const int row0 = blockIdx.x * 64;
    const int b  = row0 >> 11;
    const int t0 = row0 & 2047;
    const int col0 = blockIdx.y * 64;

    const int jc   = tid >> 4;
    const int toff = (tid & 15) * 4;
    const int tr = tid >> 4, tc = tid & 15;
    const int r0 = tr * 4, c0 = tc * 4;

    float acc[4][4] = {};

    for (int kk = 0; kk < 192; kk += 16) {
        int j = kk + jc;
        float4 v = *(const float4*)(S + ((size_t)(b * SDIM + j)) * TSQ + t0 + toff);
        As[toff][jc] = v.x; As[toff + 1][jc] = v.y; As[toff + 2][jc] = v.z; As[toff + 3][jc] = v.w;
        float4 w = *(const float4*)(spec_w + j * HD + col0 + tc * 4);
        *(float4*)&Bs[jc][tc * 4] = w;
        __syncthreads();
#pragma unroll
        for (int kc = 0; kc < 16; ++kc) {
            float a[4], bb[4];
#pragma unroll
            for (int i = 0; i < 4; ++i) a[i] = As[r0 + i][kc];
#pragma unroll
            for (int j2 = 0; j2 < 4; ++j2) bb[j2] = Bs[kc][c0 + j2];
#pragma unroll
            for (int i = 0; i < 4; ++i)
#pragma unroll
                for (int j2 = 0; j2 < 4; ++j2) acc[i][j2] += a[i] * bb[j2];
        }
        __syncthreads();
    }
#pragma unroll
    for (int i = 0; i < 4; ++i) {
        __hip_bfloat16* op = HS + ((size_t)(b * TSQ) + t0 + r0 + i) * HD + col0;
#pragma unroll
        for (int j2 = 0; j2 < 4; ++j2) op[c0 + j2] = __float2bfloat16(acc[i][j2] + spec_b[col0 + c0 + j2]);
    }
}

// ---------------- MFMA flash attention, V == K, bf16 in, fp32 out
// h-SPLIT (acc 64 AGPR, no spill) + DOUBLE-BUFFERED LDS:
// tile t in buf[t&1]; iter t computes from buf[cur] while writing t+1 into
// buf[cur^1] and issuing t+2 loads. ONE lgkmcnt(0)+barrier per iter.
// R9 was latency-bound: 12K cyc/iter vs 3.4K LDS-traffic model, MFMA+VALU+LDS
// all <30% busy -> remove the stage->barrier->compute serialization.
#define SM_K0  0
#define SM_K1  32768
#define SM_V0  65536
#define SM_V1  (65536 + 20480)
#define SM_P   (65536 + 40960)
#define SMEM_FLASH (65536 + 40960 + 10240)

__global__ __launch_bounds__(512)
void k_flash(const __hip_bfloat16* __restrict__ HTb, const __hip_bfloat16* __restrict__ HSb,
             float* __restrict__ out) {
    extern __shared__ char smem[];
    ushort* Pl = (ushort*)(smem + SM_P);    // per wave [16][40]

    const int pass = blockIdx.y;
    const int half = blockIdx.z;            // h-half: 0 -> cols 0..255, 1 -> 256..511
    const __hip_bfloat16* Qg = pass ? HSb : HTb;
    const __hip_bfloat16* Kg = pass ? HTb : HSb;
    const int b  = blockIdx.x & 7;          // batch -> XCD
    const int qt = blockIdx.x >> 3;         // 0..15
    const int tid = threadIdx.x;
    const int w = tid >> 6;
    const int l = tid & 63;
    const int c = l & 15;                   // q (and col) index
    const int g = l >> 4;                   // 4-lane-group

    ushort* Plw = Pl + w * 640;

    // staging coords: rows 2sp,2sp+1 ; h(m,n) = w*64 + gg*4 + m + 16n
    const int sp = tid & 15;
    const int sA = sp * 2, sB = sp * 2 + 1;
    const int gg = (tid >> 4) & 3;
    const int hbase = w * 64 + gg * 4;
    const int swzA = (sA & 7) << 3, swzB = (sB & 7) << 3;
    const bool myVt = (w >> 2) == half;     // waves 0-3 own h<256, 4-7 own h>=256
    const int hhbase = (w & 3) * 64 + gg * 4;

    // Q fragments: lane holds Q[q=c][k = kk*32 + g*8 .. +7]
    const __hip_bfloat16* Qrow = Qg + ((size_t)(b * TSQ) + qt * 128 + w * 16 + c) * HD;
    short8 qf[16];
#pragma unroll
    for (int kk = 0; kk < 16; ++kk) qf[kk] = *(const short8*)(Qrow + kk * 32 + g * 8);

    f32x4 acc[16];
#pragma unroll
    for (int j = 0; j < 16; ++j) acc[j] = (f32x4){0.f, 0.f, 0.f, 0.f};
    float mrow = -1e30f, lrow = 0.f;

    const __hip_bfloat16* Kb = Kg + (size_t)(b * TSQ) * HD;

    bf4 r0[4], r1[4];
    // ---- prologue: load tile0, write buf0, load tile1
#pragma unroll
    for (int n = 0; n < 4; ++n) {
        r0[n] = *(const bf4*)(Kb + (size_t)sA * HD + hbase + n * 16);
        r1[n] = *(const bf4*)(Kb + (size_t)sB * HD + hbase + n * 16);
    }
    {
        ushort* Kl0 = (ushort*)(smem + SM_K0);
        ushort* Vt0 = (ushort*)(smem + SM_V0);
#pragma unroll
        for (int n = 0; n < 4; ++n) {
            *(bf4*)&Kl0[sA * 512 + ((hbase + n * 16) ^ swzA)] = r0[n];
            *(bf4*)&Kl0[sB * 512 + ((hbase + n * 16) ^ swzB)] = r1[n];
        }
        if (myVt) {
#pragma unroll
            for (int n = 0; n < 4; ++n)
#pragma unroll
                for (int m = 0; m < 4; ++m) {
                    int hh = hhbase + n * 16 + m;
                    uint v = (uint)(ushort)r0[n][m] | ((uint)(ushort)r1[n][m] << 16);
                    *(uint*)&Vt0[hh * 40 + sA] = v;
                }
        }
    }
#pragma unroll
    for (int n = 0; n < 4; ++n) {
        r0[n] = *(const bf4*)(Kb + (size_t)(32 + sA) * HD + hbase + n * 16);
        r1[n] = *(const bf4*)(Kb + (size_t)(32 + sB) * HD + hbase + n * 16);
    }
    asm volatile("s_waitcnt lgkmcnt(0)" ::: "memory");
    __builtin_amdgcn_s_barrier();

    for (int it = 0; it < 64; ++it) {
        const int cur = it & 1;
        ushort* KlC = (ushort*)(smem + (cur ? SM_K1 : SM_K0));
        ushort* VtC = (ushort*)(smem + (cur ? SM_V1 : SM_V0));
        ushort* KlN = (ushort*)(smem + (cur ? SM_K0 : SM_K1));
        ushort* VtN = (ushort*)(smem + (cur ? SM_V0 : SM_V1));

        // ---- QK^T (swapped) from current buffer: S^T = K . Q^T
        f32x4 sv[2];
        __builtin_amdgcn_s_setprio(1);
#pragma unroll
        for (int st = 0; st < 2; ++st) {
            f32x4 s_ = (f32x4){0.f, 0.f, 0.f, 0.f};
            const int srow = st * 16 + c;
            const int swz = (srow & 7) << 3;
            const ushort* kp = KlC + srow * 512;
#pragma unroll
            for (int kk = 0; kk < 16; ++kk) {
                short8 kf = *(const short8*)(kp + ((kk * 32 + g * 8) ^ swz));
                s_ = __builtin_amdgcn_mfma_f32_16x16x32_bf16(kf, qf[kk], s_, 0, 0, 0);
            }
            sv[st] = s_;
        }
        __builtin_amdgcn_s_setprio(0);

        // ---- stage tile it+1 (in r0/r1) into next buffer; overlaps with rest
        if (it + 1 < 64) {
#pragma unroll
            for (int n = 0; n < 4; ++n) {
                *(bf4*)&KlN[sA * 512 + ((hbase + n * 16) ^ swzA)] = r0[n];
                *(bf4*)&KlN[sB * 512 + ((hbase + n * 16) ^ swzB)] = r1[n];
            }
            if (myVt) {
#pragma unroll
                for (int n = 0; n < 4; ++n)
#pragma unroll
                    for (int m = 0; m < 4; ++m) {
                        int hh = hhbase + n * 16 + m;
                        uint v = (uint)(ushort)r0[n][m] | ((uint)(ushort)r1[n][m] << 16);
                        *(uint*)&VtN[hh * 40 + sA] = v;
                    }
            }
        }
        // ---- issue loads for tile it+2
        if (it + 2 < 64) {
            const __hip_bfloat16* src = Kb + (size_t)((it + 2) * 32) * HD;
#pragma unroll
            for (int n = 0; n < 4; ++n) {
                r0[n] = *(const bf4*)(src + (size_t)sA * HD + hbase + n * 16);
                r1[n] = *(const bf4*)(src + (size_t)sB * HD + hbase + n * 16);
            }
        }

        // ---- online softmax, defer-max (lane owns q=c; s = st*16 + g*4 + r)
        float tmax = -1e30f;
#pragma unroll
        for (int st = 0; st < 2; ++st)
#pragma unroll
            for (int r = 0; r < 4; ++r) {
                float x = sv[st][r] * SCALE;
                sv[st][r] = x;
                tmax = fmaxf(tmax, x);
            }
        tmax = fmaxf(tmax, __shfl_xor(tmax, 16, 64));
        tmax = fmaxf(tmax, __shfl_xor(tmax, 32, 64));
        if (__all(tmax <= mrow + 8.0f)) {
            float tsum = 0.f;
#pragma unroll
            for (int st = 0; st < 2; ++st)
#pragma unroll
                for (int r = 0; r < 4; ++r) { float e = __expf(sv[st][r] - mrow); sv[st][r] = e; tsum += e; }
            tsum += __shfl_xor(tsum, 16, 64);
            tsum += __shfl_xor(tsum, 32, 64);
            lrow += tsum;
        } else {
            float mnew = fmaxf(mrow, tmax);
            float alpha = __expf(mrow - mnew);
            float tsum = 0.f;
#pragma unroll
            for (int st = 0; st < 2; ++st)
#pragma unroll
                for (int r = 0; r < 4; ++r) { float e = __expf(sv[st][r] - mnew); sv[st][r] = e; tsum += e; }
            tsum += __shfl_xor(tsum, 16, 64);
            tsum += __shfl_xor(tsum, 32, 64);
            lrow = lrow * alpha + tsum;
            mrow = mnew;
#pragma unroll
            for (int r = 0; r < 4; ++r) {
                float ar = __shfl(alpha, g * 4 + r, 64);
#pragma unroll
                for (int j = 0; j < 16; ++j) acc[j][r] *= ar;
            }
        }

        // ---- P (bf16 pairs) to per-wave LDS
#pragma unroll
        for (int st = 0; st < 2; ++st)
#pragma unroll
            for (int pp = 0; pp < 2; ++pp) {
                int s = st * 16 + g * 4 + pp * 2;
                uint v = (uint)(ushort)f2bf(sv[st][pp * 2]) |
                         ((uint)(ushort)f2bf(sv[st][pp * 2 + 1]) << 16);
                *(uint*)&Plw[c * 40 + s] = v;
            }

        // ---- PV over this block's h-half from current Vt
        short8 pa = *(const short8*)(Plw + c * 40 + g * 8);
        __builtin_amdgcn_s_setprio(1);
#pragma unroll
        for (int j = 0; j < 16; ++j) {
            short8 vb = *(const short8*)(VtC + (size_t)(j * 16 + c) * 40 + g * 8);
            acc[j] = __builtin_amdgcn_mfma_f32_16x16x32_bf16(pa, vb, acc[j], 0, 0, 0);
        }
        __builtin_amdgcn_s_setprio(0);

        asm volatile("s_waitcnt lgkmcnt(0)" ::: "memory");
        __builtin_amdgcn_s_barrier();
    }

    // ---- epilogue: divide by l per q-row, store this half's 256 fp32 cols
    float linv = 1.f / lrow;
    float* orow = out + ((size_t)(b * TSQ) + qt * 128 + w * 16) * 1024 + pass * HD + half * 256;
#pragma unroll
    for (int r = 0; r < 4; ++r) {
        float inv = __shfl(linv, g * 4 + r, 64);
#pragma unroll
        for (int j = 0; j < 16; ++j)
            orow[(size_t)(g * 4 + r) * 1024 + j * 16 + c] = acc[j][r] * inv;
    }
}

extern "C" void kernel_launch(void* const* d_in, const int* in_sizes, int n_in,
                              void* d_out, int out_size, void* d_ws, size_t ws_size,
                              hipStream_t stream) {
    const float* time_features = (const float*)d_in[0];
    const float* spec_features = (const float*)d_in[1];
    const float* conv_w = (const float*)d_in[2];
    const float* conv_b = (const float*)d_in[3];
    const float* time_w = (const float*)d_in[4];
    const float* time_b = (const float*)d_in[5];
    const float* spec_w = (const float*)d_in[6];
    const float* spec_b = (const float*)d_in[7];
    float* out = (float*)d_out;
    char* ws = (char*)d_ws;

    float* G  = (float*)(ws + OFFB_G);
    float* hb = (float*)(ws + OFFB_HB);
    __hip_bfloat16* HTb = (__hip_bfloat16*)(ws + OFFB_HT);
    __hip_bfloat16* HSb = (__hip_bfloat16*)(ws + OFFB_HS);

    (void)hipFuncSetAttribute((const void*)k_flash, hipFuncAttributeMaxDynamicSharedMemorySize, SMEM_FLASH);

    k_G<<<dim3(1024), 256, 0, stream>>>(conv_w, time_w, G);
    k_hbias<<<dim3(2), 256, 0, stream>>>(conv_b, time_w, time_b, hb);
    k_htime<<<dim3(128, 8, 2), 256, 0, stream>>>(time_features, G, hb, HTb);
    k_hspec<<<dim3(256, 8), 256, 0, stream>>>(spec_features, spec_w, spec_b, HSb);
    k_flash<<<dim3(128, 2, 2), 512, SMEM_FLASH, stream>>>(HTb, HSb, out);
}